// Round 3
// baseline (581.040 us; speedup 1.0000x reference)
//
#include <hip/hip_runtime.h>

#define C 128

// ---------------------------------------------------------------------------
// zero the in-degree counters
__global__ __launch_bounds__(256) void k_zero(int* __restrict__ cnt, int N) {
    int i = blockIdx.x * 256 + threadIdx.x;
    if (i < N) cnt[i] = 0;
}

// in-degree histogram: cnt[dst[e]] += 1
__global__ __launch_bounds__(256) void k_hist(const int* __restrict__ dst,
                                              int* __restrict__ cnt, int E) {
    int e = blockIdx.x * 256 + threadIdx.x;
    if (e < E) atomicAdd(&cnt[dst[e]], 1);
}

// scan step 1: per-block (256-chunk) sums of cnt
__global__ __launch_bounds__(256) void k_scan1(const int* __restrict__ cnt,
                                               int* __restrict__ partials, int N) {
    __shared__ int sdata[256];
    int i = blockIdx.x * 256 + threadIdx.x;
    sdata[threadIdx.x] = (i < N) ? cnt[i] : 0;
    __syncthreads();
    for (int s = 128; s > 0; s >>= 1) {
        if (threadIdx.x < s) sdata[threadIdx.x] += sdata[threadIdx.x + s];
        __syncthreads();
    }
    if (threadIdx.x == 0) partials[blockIdx.x] = sdata[0];
}

// scan step 2: exclusive scan of the ~196 block partials (serial, tiny)
__global__ void k_scan2(int* __restrict__ partials, int nb) {
    if (threadIdx.x == 0 && blockIdx.x == 0) {
        int run = 0;
        for (int b = 0; b < nb; ++b) {
            int v = partials[b];
            partials[b] = run;
            run += v;
        }
    }
}

// scan step 3: per-block exclusive scan + block offset -> rowptr, fillptr;
// also dinv = rsqrt(deg) with deg = cnt + 1 (self-loop)
__global__ __launch_bounds__(256) void k_scan3(const int* __restrict__ cnt,
                                               const int* __restrict__ partials,
                                               int* __restrict__ rowptr,
                                               int* __restrict__ fillptr,
                                               float* __restrict__ dinv,
                                               int N, int E) {
    __shared__ int s[2][256];
    int i = blockIdx.x * 256 + threadIdx.x;
    int v = (i < N) ? cnt[i] : 0;
    int buf = 0;
    s[0][threadIdx.x] = v;
    __syncthreads();
    for (int off = 1; off < 256; off <<= 1) {
        int t = s[buf][threadIdx.x];
        if (threadIdx.x >= off) t += s[buf][threadIdx.x - off];
        s[buf ^ 1][threadIdx.x] = t;
        buf ^= 1;
        __syncthreads();
    }
    int incl = s[buf][threadIdx.x];
    int excl = incl - v + partials[blockIdx.x];
    if (i < N) {
        rowptr[i] = excl;
        fillptr[i] = excl;
        dinv[i] = rsqrtf((float)v + 1.0f);
    }
    if (i == 0) rowptr[N] = E;
}

// fill CSR column indices: col[pos] = src[e] at pos = fillptr[dst[e]]++
__global__ __launch_bounds__(256) void k_fill(const int* __restrict__ src,
                                              const int* __restrict__ dst,
                                              int* __restrict__ fillptr,
                                              int* __restrict__ col, int E) {
    int e = blockIdx.x * 256 + threadIdx.x;
    if (e >= E) return;
    int d = dst[e];
    int pos = atomicAdd(&fillptr[d], 1);
    col[pos] = src[e];
}

// ---------------------------------------------------------------------------
// Hs[M,128] = (X[M,128] @ W[128,128]) * dinv[row]  (fp32, vector ALU)
// block = 256 threads, 32 rows per block; x-tile in LDS, W from L2.
__global__ __launch_bounds__(256) void k_gemm128s(const float* __restrict__ X,
                                                  const float* __restrict__ W,
                                                  const float* __restrict__ dinv,
                                                  float* __restrict__ Hs, int M) {
    __shared__ float xs[32][C];
    const int t = threadIdx.x;
    const int row0 = blockIdx.x * 32;

    for (int i = t; i < 1024; i += 256) {
        int idx = i * 4;
        int r = idx >> 7;
        float4 v;
        if (row0 + r < M)
            v = *(const float4*)(X + (size_t)(row0 + r) * C + (idx & 127));
        else
            v = make_float4(0.f, 0.f, 0.f, 0.f);
        *(float4*)(&xs[0][0] + idx) = v;
    }
    __syncthreads();

    const int c = t & 127;
    const int rg = t >> 7;
    float acc[16];
#pragma unroll
    for (int r = 0; r < 16; ++r) acc[r] = 0.f;

    for (int k = 0; k < C; k += 4) {
        float4 w4;
        w4.x = W[(k + 0) * C + c];
        w4.y = W[(k + 1) * C + c];
        w4.z = W[(k + 2) * C + c];
        w4.w = W[(k + 3) * C + c];
#pragma unroll
        for (int r = 0; r < 16; ++r) {
            float4 xv = *(const float4*)&xs[rg * 16 + r][k];
            acc[r] += xv.x * w4.x + xv.y * w4.y + xv.z * w4.z + xv.w * w4.w;
        }
    }

#pragma unroll
    for (int r = 0; r < 16; ++r) {
        int row = row0 + rg * 16 + r;
        if (row < M) Hs[(size_t)row * C + c] = acc[r] * dinv[row];
    }
}

// ---------------------------------------------------------------------------
// fused aggregation: Out[i] = relu(dinv[i] * (Hs[i] + sum_{j in N(i)} Hs[j]) + b)
// 2 nodes per 256-thread block; thread c of a 128-half sums channel c.
__global__ __launch_bounds__(256) void k_aggf(const float* __restrict__ Hs,
                                              const int* __restrict__ rowptr,
                                              const int* __restrict__ col,
                                              const float* __restrict__ dinv,
                                              const float* __restrict__ b,
                                              float* __restrict__ Out, int N) {
    int node = blockIdx.x * 2 + (threadIdx.x >> 7);
    int c = threadIdx.x & 127;
    if (node >= N) return;
    float acc = Hs[(size_t)node * C + c];  // self-loop (Hs already row-scaled)
    int e0 = rowptr[node], e1 = rowptr[node + 1];
    for (int j = e0; j < e1; ++j) {
        int nb = col[j];
        acc += Hs[(size_t)nb * C + c];
    }
    float v = dinv[node] * acc + b[c];
    Out[(size_t)node * C + c] = v > 0.f ? v : 0.f;
}

// ---------------------------------------------------------------------------
// classifier: out[i, j] = H[i,:] . Wl[:, j] + bl[j]   (j < 10)
__global__ __launch_bounds__(256) void k_final(const float* __restrict__ H,
                                               const float* __restrict__ Wl,
                                               const float* __restrict__ bl,
                                               float* __restrict__ out, int M) {
    __shared__ float wl[C * 10];
    __shared__ float bls[16];
    for (int i = threadIdx.x; i < C * 10; i += 256) wl[i] = Wl[i];
    if (threadIdx.x < 10) bls[threadIdx.x] = bl[threadIdx.x];
    __syncthreads();

    long long g = (long long)blockIdx.x * 256 + threadIdx.x;
    int i = (int)(g >> 4);
    int j = (int)(g & 15);
    if (i >= M || j >= 10) return;
    const float* h = H + (size_t)i * C;
    float acc = bls[j];
#pragma unroll 8
    for (int c = 0; c < C; ++c) acc += h[c] * wl[c * 10 + j];
    out[(size_t)i * 10 + j] = acc;
}

// ---------------------------------------------------------------------------
extern "C" void kernel_launch(void* const* d_in, const int* in_sizes, int n_in,
                              void* d_out, int out_size, void* d_ws, size_t ws_size,
                              hipStream_t stream) {
    const float* x  = (const float*)d_in[0];
    const int*   ei = (const int*)d_in[1];
    const float* W1 = (const float*)d_in[2];
    const float* b1 = (const float*)d_in[3];
    const float* W2 = (const float*)d_in[4];
    const float* b2 = (const float*)d_in[5];
    const float* Wl = (const float*)d_in[6];
    const float* bl = (const float*)d_in[7];
    float* out = (float*)d_out;

    const int N = in_sizes[0] / C;   // 50000
    const int E = in_sizes[1] / 2;   // 800000
    const int* src = ei;
    const int* dst = ei + E;

    char* ws = (char*)d_ws;
    const size_t HB = (size_t)N * C * sizeof(float);
    float* bufHs  = (float*)ws;                          // Hs = (X@W)*dinv
    float* bufT   = (float*)(ws + HB);                   // layer output
    char*  p      = ws + 2 * HB;
    int*   cnt     = (int*)p;            p += (size_t)N * 4;
    int*   rowptr  = (int*)p;            p += (size_t)(N + 1) * 4;
    int*   fillptr = (int*)p;            p += (size_t)N * 4;
    int*   colidx  = (int*)p;            p += (size_t)E * 4;
    float* dinv    = (float*)p;          p += (size_t)N * 4;
    int*   partials= (int*)p;

    const int gridN   = (N + 255) / 256;       // 196
    const int gridE   = (E + 255) / 256;       // 3125
    const int gridGemm = (N + 31) / 32;        // 1563
    const int gridAgg = (N + 1) / 2;           // 25000
    const int gridFin = (int)(((long long)N * 16 + 255) / 256);

    // CSR build (once; shared by both layers)
    k_zero<<<gridN, 256, 0, stream>>>(cnt, N);
    k_hist<<<gridE, 256, 0, stream>>>(dst, cnt, E);
    k_scan1<<<gridN, 256, 0, stream>>>(cnt, partials, N);
    k_scan2<<<1, 64, 0, stream>>>(partials, gridN);
    k_scan3<<<gridN, 256, 0, stream>>>(cnt, partials, rowptr, fillptr, dinv, N, E);
    k_fill<<<gridE, 256, 0, stream>>>(src, dst, fillptr, colidx, E);

    // layer 1
    k_gemm128s<<<gridGemm, 256, 0, stream>>>(x, W1, dinv, bufHs, N);
    k_aggf<<<gridAgg, 256, 0, stream>>>(bufHs, rowptr, colidx, dinv, b1, bufT, N);

    // layer 2
    k_gemm128s<<<gridGemm, 256, 0, stream>>>(bufT, W2, dinv, bufHs, N);
    k_aggf<<<gridAgg, 256, 0, stream>>>(bufHs, rowptr, colidx, dinv, b2, bufT, N);

    // classifier
    k_final<<<gridFin, 256, 0, stream>>>(bufT, Wl, bl, out, N);
}

// Round 4
// 397.535 us; speedup vs baseline: 1.4616x; 1.4616x over previous
//
#include <hip/hip_runtime.h>

#define C 128

// ---------------------------------------------------------------------------
// zero the in-degree counters
__global__ __launch_bounds__(256) void k_zero(int* __restrict__ cnt, int N) {
    int i = blockIdx.x * 256 + threadIdx.x;
    if (i < N) cnt[i] = 0;
}

// in-degree histogram: cnt[dst[e]] += 1
__global__ __launch_bounds__(256) void k_hist(const int* __restrict__ dst,
                                              int* __restrict__ cnt, int E) {
    int e = blockIdx.x * 256 + threadIdx.x;
    if (e < E) atomicAdd(&cnt[dst[e]], 1);
}

// scan step 1: per-block (256-chunk) sums of cnt
__global__ __launch_bounds__(256) void k_scan1(const int* __restrict__ cnt,
                                               int* __restrict__ partials, int N) {
    __shared__ int sdata[256];
    int i = blockIdx.x * 256 + threadIdx.x;
    sdata[threadIdx.x] = (i < N) ? cnt[i] : 0;
    __syncthreads();
    for (int s = 128; s > 0; s >>= 1) {
        if (threadIdx.x < s) sdata[threadIdx.x] += sdata[threadIdx.x + s];
        __syncthreads();
    }
    if (threadIdx.x == 0) partials[blockIdx.x] = sdata[0];
}

// scan step 2: exclusive scan of the block partials (parallel, nb <= 256)
__global__ __launch_bounds__(256) void k_scan2(int* __restrict__ partials, int nb) {
    __shared__ int s[2][256];
    int t = threadIdx.x;
    if (nb <= 256) {
        int v = (t < nb) ? partials[t] : 0;
        int buf = 0;
        s[0][t] = v;
        __syncthreads();
        for (int off = 1; off < 256; off <<= 1) {
            int x = s[buf][t];
            if (t >= off) x += s[buf][t - off];
            s[buf ^ 1][t] = x;
            buf ^= 1;
            __syncthreads();
        }
        if (t < nb) partials[t] = s[buf][t] - v;  // exclusive
    } else if (t == 0) {
        int run = 0;
        for (int b = 0; b < nb; ++b) { int v = partials[b]; partials[b] = run; run += v; }
    }
}

// scan step 3: per-block exclusive scan + block offset -> rowptr, fillptr;
// also dinv = rsqrt(deg) with deg = cnt + 1 (self-loop)
__global__ __launch_bounds__(256) void k_scan3(const int* __restrict__ cnt,
                                               const int* __restrict__ partials,
                                               int* __restrict__ rowptr,
                                               int* __restrict__ fillptr,
                                               float* __restrict__ dinv,
                                               int N, int E) {
    __shared__ int s[2][256];
    int i = blockIdx.x * 256 + threadIdx.x;
    int v = (i < N) ? cnt[i] : 0;
    int buf = 0;
    s[0][threadIdx.x] = v;
    __syncthreads();
    for (int off = 1; off < 256; off <<= 1) {
        int t = s[buf][threadIdx.x];
        if (threadIdx.x >= off) t += s[buf][threadIdx.x - off];
        s[buf ^ 1][threadIdx.x] = t;
        buf ^= 1;
        __syncthreads();
    }
    int incl = s[buf][threadIdx.x];
    int excl = incl - v + partials[blockIdx.x];
    if (i < N) {
        rowptr[i] = excl;
        fillptr[i] = excl;
        dinv[i] = rsqrtf((float)v + 1.0f);
    }
    if (i == 0) rowptr[N] = E;
}

// fill CSR column indices: col[pos] = src[e] at pos = fillptr[dst[e]]++
__global__ __launch_bounds__(256) void k_fill(const int* __restrict__ src,
                                              const int* __restrict__ dst,
                                              int* __restrict__ fillptr,
                                              int* __restrict__ col, int E) {
    int e = blockIdx.x * 256 + threadIdx.x;
    if (e >= E) return;
    int d = dst[e];
    int pos = atomicAdd(&fillptr[d], 1);
    col[pos] = src[e];
}

// ---------------------------------------------------------------------------
// Hs[M,128] = (X[M,128] @ W[128,128]) * dinv[row]  (fp32, vector ALU)
// block = 256 threads, 32 rows per block; x-tile in LDS, W column streamed
// from L2 with register double-buffering (prefetch next k-chunk).
__global__ __launch_bounds__(256) void k_gemm128s(const float* __restrict__ X,
                                                  const float* __restrict__ W,
                                                  const float* __restrict__ dinv,
                                                  float* __restrict__ Hs, int M) {
    __shared__ float xs[32][C];
    const int t = threadIdx.x;
    const int row0 = blockIdx.x * 32;

    for (int i = t; i < 1024; i += 256) {
        int idx = i * 4;
        int r = idx >> 7;
        float4 v;
        if (row0 + r < M)
            v = *(const float4*)(X + (size_t)(row0 + r) * C + (idx & 127));
        else
            v = make_float4(0.f, 0.f, 0.f, 0.f);
        *(float4*)(&xs[0][0] + idx) = v;
    }
    __syncthreads();

    const int c = t & 127;
    const int rg = t >> 7;
    float acc[16];
#pragma unroll
    for (int r = 0; r < 16; ++r) acc[r] = 0.f;

    // prefetch first W chunk
    float4 w;
    w.x = W[0 * C + c];
    w.y = W[1 * C + c];
    w.z = W[2 * C + c];
    w.w = W[3 * C + c];

    for (int k = 0; k < C; k += 4) {
        // prefetch next chunk ((k+4) wraps to 0 on last iter: harmless, valid)
        const int kn = (k + 4) & 127;
        float4 wn;
        wn.x = W[(kn + 0) * C + c];
        wn.y = W[(kn + 1) * C + c];
        wn.z = W[(kn + 2) * C + c];
        wn.w = W[(kn + 3) * C + c];
#pragma unroll
        for (int r = 0; r < 16; ++r) {
            float4 xv = *(const float4*)&xs[rg * 16 + r][k];
            acc[r] += xv.x * w.x + xv.y * w.y + xv.z * w.z + xv.w * w.w;
        }
        w = wn;
    }

#pragma unroll
    for (int r = 0; r < 16; ++r) {
        int row = row0 + rg * 16 + r;
        if (row < M) Hs[(size_t)row * C + c] = acc[r] * dinv[row];
    }
}

// ---------------------------------------------------------------------------
// fused aggregation: Out[i] = relu(dinv[i] * (Hs[i] + sum_{j in N(i)} Hs[j]) + b)
// 32 lanes per node, float4 per lane (16 B gathers), 4-neighbor unroll.
__global__ __launch_bounds__(256) void k_aggf(const float* __restrict__ Hs,
                                              const int* __restrict__ rowptr,
                                              const int* __restrict__ col,
                                              const float* __restrict__ dinv,
                                              const float* __restrict__ b,
                                              float* __restrict__ Out, int N) {
    const int node = blockIdx.x * 8 + (threadIdx.x >> 5);
    const int lane = threadIdx.x & 31;
    if (node >= N) return;
    const float4* __restrict__ H4 = (const float4*)Hs;

    float4 acc = H4[(size_t)node * 32 + lane];  // self-loop (Hs already row-scaled)
    const int e0 = rowptr[node], e1 = rowptr[node + 1];
    int j = e0;
    for (; j + 4 <= e1; j += 4) {
        int n0 = col[j + 0], n1 = col[j + 1], n2 = col[j + 2], n3 = col[j + 3];
        float4 v0 = H4[(size_t)n0 * 32 + lane];
        float4 v1 = H4[(size_t)n1 * 32 + lane];
        float4 v2 = H4[(size_t)n2 * 32 + lane];
        float4 v3 = H4[(size_t)n3 * 32 + lane];
        acc.x += (v0.x + v1.x) + (v2.x + v3.x);
        acc.y += (v0.y + v1.y) + (v2.y + v3.y);
        acc.z += (v0.z + v1.z) + (v2.z + v3.z);
        acc.w += (v0.w + v1.w) + (v2.w + v3.w);
    }
    for (; j < e1; ++j) {
        int n = col[j];
        float4 v = H4[(size_t)n * 32 + lane];
        acc.x += v.x; acc.y += v.y; acc.z += v.z; acc.w += v.w;
    }
    const float s = dinv[node];
    const float4 bb = *(const float4*)(b + lane * 4);
    float4 o;
    o.x = s * acc.x + bb.x; o.y = s * acc.y + bb.y;
    o.z = s * acc.z + bb.z; o.w = s * acc.w + bb.w;
    o.x = o.x > 0.f ? o.x : 0.f;
    o.y = o.y > 0.f ? o.y : 0.f;
    o.z = o.z > 0.f ? o.z : 0.f;
    o.w = o.w > 0.f ? o.w : 0.f;
    ((float4*)Out)[(size_t)node * 32 + lane] = o;
}

// ---------------------------------------------------------------------------
// classifier: out[i, j] = H[i,:] . Wl[:, j] + bl[j]   (j < 10), float4 h reads
__global__ __launch_bounds__(256) void k_final(const float* __restrict__ H,
                                               const float* __restrict__ Wl,
                                               const float* __restrict__ bl,
                                               float* __restrict__ out, int M) {
    __shared__ float wl[C * 10];
    __shared__ float bls[16];
    for (int i = threadIdx.x; i < C * 10; i += 256) wl[i] = Wl[i];
    if (threadIdx.x < 10) bls[threadIdx.x] = bl[threadIdx.x];
    __syncthreads();

    long long g = (long long)blockIdx.x * 256 + threadIdx.x;
    int i = (int)(g >> 4);
    int j = (int)(g & 15);
    if (i >= M || j >= 10) return;
    const float4* h4 = (const float4*)(H + (size_t)i * C);
    float acc = bls[j];
#pragma unroll 8
    for (int c4 = 0; c4 < 32; ++c4) {
        float4 hv = h4[c4];
        int cb = c4 * 4;
        acc += hv.x * wl[(cb + 0) * 10 + j] + hv.y * wl[(cb + 1) * 10 + j] +
               hv.z * wl[(cb + 2) * 10 + j] + hv.w * wl[(cb + 3) * 10 + j];
    }
    out[(size_t)i * 10 + j] = acc;
}

// ---------------------------------------------------------------------------
extern "C" void kernel_launch(void* const* d_in, const int* in_sizes, int n_in,
                              void* d_out, int out_size, void* d_ws, size_t ws_size,
                              hipStream_t stream) {
    const float* x  = (const float*)d_in[0];
    const int*   ei = (const int*)d_in[1];
    const float* W1 = (const float*)d_in[2];
    const float* b1 = (const float*)d_in[3];
    const float* W2 = (const float*)d_in[4];
    const float* b2 = (const float*)d_in[5];
    const float* Wl = (const float*)d_in[6];
    const float* bl = (const float*)d_in[7];
    float* out = (float*)d_out;

    const int N = in_sizes[0] / C;   // 50000
    const int E = in_sizes[1] / 2;   // 800000
    const int* src = ei;
    const int* dst = ei + E;

    char* ws = (char*)d_ws;
    const size_t HB = (size_t)N * C * sizeof(float);
    float* bufHs  = (float*)ws;                          // Hs = (X@W)*dinv
    float* bufT   = (float*)(ws + HB);                   // layer output
    char*  p      = ws + 2 * HB;
    int*   cnt     = (int*)p;            p += (size_t)N * 4;
    int*   rowptr  = (int*)p;            p += (size_t)(N + 1) * 4;
    int*   fillptr = (int*)p;            p += (size_t)N * 4;
    int*   colidx  = (int*)p;            p += (size_t)E * 4;
    float* dinv    = (float*)p;          p += (size_t)N * 4;
    int*   partials= (int*)p;

    const int gridN   = (N + 255) / 256;       // 196
    const int gridE   = (E + 255) / 256;       // 3125
    const int gridGemm = (N + 31) / 32;        // 1563
    const int gridAgg = (N + 7) / 8;           // 6250
    const int gridFin = (int)(((long long)N * 16 + 255) / 256);

    // CSR build (once; shared by both layers)
    k_zero<<<gridN, 256, 0, stream>>>(cnt, N);
    k_hist<<<gridE, 256, 0, stream>>>(dst, cnt, E);
    k_scan1<<<gridN, 256, 0, stream>>>(cnt, partials, N);
    k_scan2<<<1, 256, 0, stream>>>(partials, gridN);
    k_scan3<<<gridN, 256, 0, stream>>>(cnt, partials, rowptr, fillptr, dinv, N, E);
    k_fill<<<gridE, 256, 0, stream>>>(src, dst, fillptr, colidx, E);

    // layer 1
    k_gemm128s<<<gridGemm, 256, 0, stream>>>(x, W1, dinv, bufHs, N);
    k_aggf<<<gridAgg, 256, 0, stream>>>(bufHs, rowptr, colidx, dinv, b1, bufT, N);

    // layer 2
    k_gemm128s<<<gridGemm, 256, 0, stream>>>(bufT, W2, dinv, bufHs, N);
    k_aggf<<<gridAgg, 256, 0, stream>>>(bufHs, rowptr, colidx, dinv, b2, bufT, N);

    // classifier
    k_final<<<gridFin, 256, 0, stream>>>(bufT, Wl, bl, out, N);
}

// Round 5
// 337.098 us; speedup vs baseline: 1.7237x; 1.1793x over previous
//
#include <hip/hip_runtime.h>
#include <hip/hip_fp16.h>

#define C 128

// ---------------------------------------------------------------------------
// zero the in-degree counters
__global__ __launch_bounds__(256) void k_zero(int* __restrict__ cnt, int N) {
    int i = blockIdx.x * 256 + threadIdx.x;
    if (i < N) cnt[i] = 0;
}

// in-degree histogram: cnt[dst[e]] += 1
__global__ __launch_bounds__(256) void k_hist(const int* __restrict__ dst,
                                              int* __restrict__ cnt, int E) {
    int e = blockIdx.x * 256 + threadIdx.x;
    if (e < E) atomicAdd(&cnt[dst[e]], 1);
}

// scan step 1: per-block (256-chunk) sums of cnt
__global__ __launch_bounds__(256) void k_scan1(const int* __restrict__ cnt,
                                               int* __restrict__ partials, int N) {
    __shared__ int sdata[256];
    int i = blockIdx.x * 256 + threadIdx.x;
    sdata[threadIdx.x] = (i < N) ? cnt[i] : 0;
    __syncthreads();
    for (int s = 128; s > 0; s >>= 1) {
        if (threadIdx.x < s) sdata[threadIdx.x] += sdata[threadIdx.x + s];
        __syncthreads();
    }
    if (threadIdx.x == 0) partials[blockIdx.x] = sdata[0];
}

// scan step 2: exclusive scan of the block partials (parallel, nb <= 256)
__global__ __launch_bounds__(256) void k_scan2(int* __restrict__ partials, int nb) {
    __shared__ int s[2][256];
    int t = threadIdx.x;
    if (nb <= 256) {
        int v = (t < nb) ? partials[t] : 0;
        int buf = 0;
        s[0][t] = v;
        __syncthreads();
        for (int off = 1; off < 256; off <<= 1) {
            int x = s[buf][t];
            if (t >= off) x += s[buf][t - off];
            s[buf ^ 1][t] = x;
            buf ^= 1;
            __syncthreads();
        }
        if (t < nb) partials[t] = s[buf][t] - v;  // exclusive
    } else if (t == 0) {
        int run = 0;
        for (int b = 0; b < nb; ++b) { int v = partials[b]; partials[b] = run; run += v; }
    }
}

// scan step 3: per-block exclusive scan + block offset -> rowptr, fillptr;
// also dinv = rsqrt(deg) with deg = cnt + 1 (self-loop)
__global__ __launch_bounds__(256) void k_scan3(const int* __restrict__ cnt,
                                               const int* __restrict__ partials,
                                               int* __restrict__ rowptr,
                                               int* __restrict__ fillptr,
                                               float* __restrict__ dinv,
                                               int N, int E) {
    __shared__ int s[2][256];
    int i = blockIdx.x * 256 + threadIdx.x;
    int v = (i < N) ? cnt[i] : 0;
    int buf = 0;
    s[0][threadIdx.x] = v;
    __syncthreads();
    for (int off = 1; off < 256; off <<= 1) {
        int t = s[buf][threadIdx.x];
        if (threadIdx.x >= off) t += s[buf][threadIdx.x - off];
        s[buf ^ 1][threadIdx.x] = t;
        buf ^= 1;
        __syncthreads();
    }
    int incl = s[buf][threadIdx.x];
    int excl = incl - v + partials[blockIdx.x];
    if (i < N) {
        rowptr[i] = excl;
        fillptr[i] = excl;
        dinv[i] = rsqrtf((float)v + 1.0f);
    }
    if (i == 0) rowptr[N] = E;
}

// fill CSR column indices: col[pos] = src[e] at pos = fillptr[dst[e]]++
__global__ __launch_bounds__(256) void k_fill(const int* __restrict__ src,
                                              const int* __restrict__ dst,
                                              int* __restrict__ fillptr,
                                              int* __restrict__ col, int E) {
    int e = blockIdx.x * 256 + threadIdx.x;
    if (e >= E) return;
    int d = dst[e];
    int pos = atomicAdd(&fillptr[d], 1);
    col[pos] = src[e];
}

// ---------------------------------------------------------------------------
// Hs = (X @ W) * dinv[row], written both fp32 (self-term) and fp16 (gather).
// 256 threads, 32 rows/block; thread computes 4 rows x 4 cols (register tile).
// W staged in LDS in two 64-row halves (32 KB) + X tile (16 KB) = 48 KB.
__global__ __launch_bounds__(256) void k_gemm_rt(const float* __restrict__ X,
                                                 const float* __restrict__ W,
                                                 const float* __restrict__ dinv,
                                                 float* __restrict__ Hs32,
                                                 __half* __restrict__ Hs16, int M) {
    __shared__ float wsl[64][C];  // 32 KB: one K-half of W
    __shared__ float xs[32][C];   // 16 KB
    const int t = threadIdx.x;
    const int row0 = blockIdx.x * 32;

    // stage X tile (once)
    for (int i = t; i < 1024; i += 256) {
        int idx = i * 4;
        int r = idx >> 7;
        float4 v = make_float4(0.f, 0.f, 0.f, 0.f);
        if (row0 + r < M)
            v = *(const float4*)(X + (size_t)(row0 + r) * C + (idx & 127));
        *(float4*)(&xs[0][0] + idx) = v;
    }

    const int tc4 = (t & 31) * 4;  // cols tc4..tc4+3
    const int tr4 = (t >> 5) * 4;  // rows tr4..tr4+3 (within tile)
    float4 acc[4];
#pragma unroll
    for (int i = 0; i < 4; ++i) acc[i] = make_float4(0.f, 0.f, 0.f, 0.f);

    for (int half = 0; half < 2; ++half) {
        const int kbase = half * 64;
        __syncthreads();  // half 0: before-use barrier; half 1: protect wsl reuse
        for (int i = t; i < 2048; i += 256)
            ((float4*)&wsl[0][0])[i] = ((const float4*)(W + (size_t)kbase * C))[i];
        __syncthreads();

#pragma unroll 4
        for (int k0 = 0; k0 < 64; k0 += 4) {
            float4 w0 = *(const float4*)&wsl[k0 + 0][tc4];
            float4 w1 = *(const float4*)&wsl[k0 + 1][tc4];
            float4 w2 = *(const float4*)&wsl[k0 + 2][tc4];
            float4 w3 = *(const float4*)&wsl[k0 + 3][tc4];
#pragma unroll
            for (int i = 0; i < 4; ++i) {
                float4 xv = *(const float4*)&xs[tr4 + i][kbase + k0];
                acc[i].x += xv.x * w0.x + xv.y * w1.x + xv.z * w2.x + xv.w * w3.x;
                acc[i].y += xv.x * w0.y + xv.y * w1.y + xv.z * w2.y + xv.w * w3.y;
                acc[i].z += xv.x * w0.z + xv.y * w1.z + xv.z * w2.z + xv.w * w3.z;
                acc[i].w += xv.x * w0.w + xv.y * w1.w + xv.z * w2.w + xv.w * w3.w;
            }
        }
    }

#pragma unroll
    for (int i = 0; i < 4; ++i) {
        int row = row0 + tr4 + i;
        if (row >= M) break;
        float s = dinv[row];
        float4 y;
        y.x = acc[i].x * s; y.y = acc[i].y * s;
        y.z = acc[i].z * s; y.w = acc[i].w * s;
        *(float4*)(Hs32 + (size_t)row * C + tc4) = y;
        __half2 p01 = __floats2half2_rn(y.x, y.y);
        __half2 p23 = __floats2half2_rn(y.z, y.w);
        uint2 pk;
        pk.x = *(unsigned int*)&p01;
        pk.y = *(unsigned int*)&p23;
        *(uint2*)(Hs16 + (size_t)row * C + tc4) = pk;
    }
}

// ---------------------------------------------------------------------------
// fused aggregation: Out[i] = relu(dinv[i]*(Hs[i] + sum_{j in N(i)} Hs16[j]) + b)
// 32 lanes per node; neighbors gathered as fp16 (8 B/lane), self-term fp32.
__global__ __launch_bounds__(256) void k_aggf(const float* __restrict__ Hs32,
                                              const __half* __restrict__ Hs16,
                                              const int* __restrict__ rowptr,
                                              const int* __restrict__ col,
                                              const float* __restrict__ dinv,
                                              const float* __restrict__ b,
                                              float* __restrict__ Out, int N) {
    const int node = blockIdx.x * 8 + (threadIdx.x >> 5);
    const int lane = threadIdx.x & 31;
    if (node >= N) return;
    const uint2* __restrict__ H16 = (const uint2*)Hs16;  // row stride 32 uint2

    float4 acc = ((const float4*)Hs32)[(size_t)node * 32 + lane];  // self-loop
    const int e0 = rowptr[node], e1 = rowptr[node + 1];
    int j = e0;
    for (; j + 4 <= e1; j += 4) {
        int n0 = col[j + 0], n1 = col[j + 1], n2 = col[j + 2], n3 = col[j + 3];
        uint2 q0 = H16[(size_t)n0 * 32 + lane];
        uint2 q1 = H16[(size_t)n1 * 32 + lane];
        uint2 q2 = H16[(size_t)n2 * 32 + lane];
        uint2 q3 = H16[(size_t)n3 * 32 + lane];
        float2 a0 = __half22float2(*(__half2*)&q0.x), b0 = __half22float2(*(__half2*)&q0.y);
        float2 a1 = __half22float2(*(__half2*)&q1.x), b1_ = __half22float2(*(__half2*)&q1.y);
        float2 a2 = __half22float2(*(__half2*)&q2.x), b2_ = __half22float2(*(__half2*)&q2.y);
        float2 a3 = __half22float2(*(__half2*)&q3.x), b3_ = __half22float2(*(__half2*)&q3.y);
        acc.x += (a0.x + a1.x) + (a2.x + a3.x);
        acc.y += (a0.y + a1.y) + (a2.y + a3.y);
        acc.z += (b0.x + b1_.x) + (b2_.x + b3_.x);
        acc.w += (b0.y + b1_.y) + (b2_.y + b3_.y);
    }
    for (; j < e1; ++j) {
        int n = col[j];
        uint2 q = H16[(size_t)n * 32 + lane];
        float2 a = __half22float2(*(__half2*)&q.x);
        float2 c = __half22float2(*(__half2*)&q.y);
        acc.x += a.x; acc.y += a.y; acc.z += c.x; acc.w += c.y;
    }
    const float s = dinv[node];
    const float4 bb = *(const float4*)(b + lane * 4);
    float4 o;
    o.x = s * acc.x + bb.x; o.y = s * acc.y + bb.y;
    o.z = s * acc.z + bb.z; o.w = s * acc.w + bb.w;
    o.x = o.x > 0.f ? o.x : 0.f;
    o.y = o.y > 0.f ? o.y : 0.f;
    o.z = o.z > 0.f ? o.z : 0.f;
    o.w = o.w > 0.f ? o.w : 0.f;
    ((float4*)Out)[(size_t)node * 32 + lane] = o;
}

// ---------------------------------------------------------------------------
// classifier: out[i, j] = H[i,:] . Wl[:, j] + bl[j]   (j < 10), float4 h reads
__global__ __launch_bounds__(256) void k_final(const float* __restrict__ H,
                                               const float* __restrict__ Wl,
                                               const float* __restrict__ bl,
                                               float* __restrict__ out, int M) {
    __shared__ float wl[C * 10];
    __shared__ float bls[16];
    for (int i = threadIdx.x; i < C * 10; i += 256) wl[i] = Wl[i];
    if (threadIdx.x < 10) bls[threadIdx.x] = bl[threadIdx.x];
    __syncthreads();

    long long g = (long long)blockIdx.x * 256 + threadIdx.x;
    int i = (int)(g >> 4);
    int j = (int)(g & 15);
    if (i >= M || j >= 10) return;
    const float4* h4 = (const float4*)(H + (size_t)i * C);
    float acc = bls[j];
#pragma unroll 8
    for (int c4 = 0; c4 < 32; ++c4) {
        float4 hv = h4[c4];
        int cb = c4 * 4;
        acc += hv.x * wl[(cb + 0) * 10 + j] + hv.y * wl[(cb + 1) * 10 + j] +
               hv.z * wl[(cb + 2) * 10 + j] + hv.w * wl[(cb + 3) * 10 + j];
    }
    out[(size_t)i * 10 + j] = acc;
}

// ---------------------------------------------------------------------------
extern "C" void kernel_launch(void* const* d_in, const int* in_sizes, int n_in,
                              void* d_out, int out_size, void* d_ws, size_t ws_size,
                              hipStream_t stream) {
    const float* x  = (const float*)d_in[0];
    const int*   ei = (const int*)d_in[1];
    const float* W1 = (const float*)d_in[2];
    const float* b1 = (const float*)d_in[3];
    const float* W2 = (const float*)d_in[4];
    const float* b2 = (const float*)d_in[5];
    const float* Wl = (const float*)d_in[6];
    const float* bl = (const float*)d_in[7];
    float* out = (float*)d_out;

    const int N = in_sizes[0] / C;   // 50000
    const int E = in_sizes[1] / 2;   // 800000
    const int* src = ei;
    const int* dst = ei + E;

    char* ws = (char*)d_ws;
    const size_t HB = (size_t)N * C * sizeof(float);   // 25.6 MB
    float*  bufHs32 = (float*)ws;
    __half* bufHs16 = (__half*)(ws + HB);
    float*  bufT    = (float*)(ws + HB + HB / 2);
    char*   p       = ws + 2 * HB + HB / 2;
    int*   cnt      = (int*)p;           p += (size_t)N * 4;
    int*   rowptr   = (int*)p;           p += (size_t)(N + 1) * 4;
    int*   fillptr  = (int*)p;           p += (size_t)N * 4;
    int*   colidx   = (int*)p;           p += (size_t)E * 4;
    float* dinv     = (float*)p;         p += (size_t)N * 4;
    int*   partials = (int*)p;

    const int gridN   = (N + 255) / 256;       // 196
    const int gridE   = (E + 255) / 256;       // 3125
    const int gridGemm = (N + 31) / 32;        // 1563
    const int gridAgg = (N + 7) / 8;           // 6250
    const int gridFin = (int)(((long long)N * 16 + 255) / 256);

    // CSR build (once; shared by both layers)
    k_zero<<<gridN, 256, 0, stream>>>(cnt, N);
    k_hist<<<gridE, 256, 0, stream>>>(dst, cnt, E);
    k_scan1<<<gridN, 256, 0, stream>>>(cnt, partials, N);
    k_scan2<<<1, 256, 0, stream>>>(partials, gridN);
    k_scan3<<<gridN, 256, 0, stream>>>(cnt, partials, rowptr, fillptr, dinv, N, E);
    k_fill<<<gridE, 256, 0, stream>>>(src, dst, fillptr, colidx, E);

    // layer 1
    k_gemm_rt<<<gridGemm, 256, 0, stream>>>(x, W1, dinv, bufHs32, bufHs16, N);
    k_aggf<<<gridAgg, 256, 0, stream>>>(bufHs32, bufHs16, rowptr, colidx, dinv, b1, bufT, N);

    // layer 2
    k_gemm_rt<<<gridGemm, 256, 0, stream>>>(bufT, W2, dinv, bufHs32, bufHs16, N);
    k_aggf<<<gridAgg, 256, 0, stream>>>(bufHs32, bufHs16, rowptr, colidx, dinv, b2, bufT, N);

    // classifier
    k_final<<<gridFin, 256, 0, stream>>>(bufT, Wl, bl, out, N);
}

// Round 6
// 266.692 us; speedup vs baseline: 2.1787x; 1.2640x over previous
//
#include <hip/hip_runtime.h>
#include <hip/hip_fp16.h>

#define C 128

typedef _Float16 half8 __attribute__((ext_vector_type(8)));
typedef float f32x4 __attribute__((ext_vector_type(4)));

// ---------------------------------------------------------------------------
// zero the in-degree counters
__global__ __launch_bounds__(256) void k_zero(int* __restrict__ cnt, int N) {
    int i = blockIdx.x * 256 + threadIdx.x;
    if (i < N) cnt[i] = 0;
}

// in-degree histogram + per-edge rank: rank[e] = old count of dst[e]
__global__ __launch_bounds__(256) void k_histr(const int* __restrict__ dst,
                                               int* __restrict__ cnt,
                                               unsigned short* __restrict__ rank,
                                               int E) {
    int e = blockIdx.x * 256 + threadIdx.x;
    if (e < E) rank[e] = (unsigned short)atomicAdd(&cnt[dst[e]], 1);
}

// scan step 1: per-block (256-chunk) sums of cnt
__global__ __launch_bounds__(256) void k_scan1(const int* __restrict__ cnt,
                                               int* __restrict__ partials, int N) {
    __shared__ int sdata[256];
    int i = blockIdx.x * 256 + threadIdx.x;
    sdata[threadIdx.x] = (i < N) ? cnt[i] : 0;
    __syncthreads();
    for (int s = 128; s > 0; s >>= 1) {
        if (threadIdx.x < s) sdata[threadIdx.x] += sdata[threadIdx.x + s];
        __syncthreads();
    }
    if (threadIdx.x == 0) partials[blockIdx.x] = sdata[0];
}

// scan step 2: exclusive scan of the block partials (parallel, nb <= 256)
__global__ __launch_bounds__(256) void k_scan2(int* __restrict__ partials, int nb) {
    __shared__ int s[2][256];
    int t = threadIdx.x;
    if (nb <= 256) {
        int v = (t < nb) ? partials[t] : 0;
        int buf = 0;
        s[0][t] = v;
        __syncthreads();
        for (int off = 1; off < 256; off <<= 1) {
            int x = s[buf][t];
            if (t >= off) x += s[buf][t - off];
            s[buf ^ 1][t] = x;
            buf ^= 1;
            __syncthreads();
        }
        if (t < nb) partials[t] = s[buf][t] - v;  // exclusive
    } else if (t == 0) {
        int run = 0;
        for (int b = 0; b < nb; ++b) { int v = partials[b]; partials[b] = run; run += v; }
    }
}

// scan step 3: rowptr (exclusive scan) + dinv = rsqrt(deg), deg = cnt + 1
__global__ __launch_bounds__(256) void k_scan3(const int* __restrict__ cnt,
                                               const int* __restrict__ partials,
                                               int* __restrict__ rowptr,
                                               float* __restrict__ dinv,
                                               int N, int E) {
    __shared__ int s[2][256];
    int i = blockIdx.x * 256 + threadIdx.x;
    int v = (i < N) ? cnt[i] : 0;
    int buf = 0;
    s[0][threadIdx.x] = v;
    __syncthreads();
    for (int off = 1; off < 256; off <<= 1) {
        int t = s[buf][threadIdx.x];
        if (threadIdx.x >= off) t += s[buf][threadIdx.x - off];
        s[buf ^ 1][threadIdx.x] = t;
        buf ^= 1;
        __syncthreads();
    }
    int incl = s[buf][threadIdx.x];
    int excl = incl - v + partials[blockIdx.x];
    if (i < N) {
        rowptr[i] = excl;
        dinv[i] = rsqrtf((float)v + 1.0f);
    }
    if (i == 0) rowptr[N] = E;
}

// fill CSR columns (atomic-free): col[rowptr[dst]+rank] = src  (uint16)
__global__ __launch_bounds__(256) void k_fill2(const int* __restrict__ src,
                                               const int* __restrict__ dst,
                                               const unsigned short* __restrict__ rank,
                                               const int* __restrict__ rowptr,
                                               unsigned short* __restrict__ col, int E) {
    int e = blockIdx.x * 256 + threadIdx.x;
    if (e >= E) return;
    int pos = rowptr[dst[e]] + (int)rank[e];
    col[pos] = (unsigned short)src[e];
}

// ---------------------------------------------------------------------------
// Hs16 = fp16((X @ W) * dinv[row]) via split-precision f16 MFMA.
// Block 256 thr = 4 waves, 64 rows; W^T hi/lo in LDS (64 KB, XOR-swizzled);
// A fragments straight from global (row = lane&15, k = (lane>>4)*8+j).
__global__ __launch_bounds__(256) void k_gemm_mfma(const float* __restrict__ X,
                                                   const float* __restrict__ W,
                                                   const float* __restrict__ dinv,
                                                   _Float16* __restrict__ Hs16,
                                                   int M) {
    __shared__ _Float16 WtH[C * C];
    __shared__ _Float16 WtL[C * C];
    const int t = threadIdx.x;

    // stage W^T hi/lo, XOR-swizzling the 16B (8-half) chunk index with n&15
    for (int idx = t; idx < C * C; idx += 256) {
        int k = idx >> 7, n = idx & 127;
        float w = W[idx];
        _Float16 h = (_Float16)w;
        _Float16 l = (_Float16)(w - (float)h);
        int off = n * C + (((k >> 3) ^ (n & 15)) << 3) + (k & 7);
        WtH[off] = h;
        WtL[off] = l;
    }
    __syncthreads();

    const int wv = t >> 6, lane = t & 63;
    const int l15 = lane & 15, lg = lane >> 4;  // lg = k-group (0..3)
    const int rowA = blockIdx.x * 64 + wv * 16 + l15;
    const bool aok = rowA < M;
    const float* xrow = X + (size_t)rowA * C;

    f32x4 acc[8];
#pragma unroll
    for (int i = 0; i < 8; ++i) acc[i] = (f32x4){0.f, 0.f, 0.f, 0.f};

#pragma unroll
    for (int ks = 0; ks < 4; ++ks) {
        const int k0 = ks * 32 + lg * 8;
        float4 x0 = make_float4(0.f, 0.f, 0.f, 0.f);
        float4 x1 = make_float4(0.f, 0.f, 0.f, 0.f);
        if (aok) {
            x0 = *(const float4*)(xrow + k0);
            x1 = *(const float4*)(xrow + k0 + 4);
        }
        half8 ah, al;
        {
            _Float16 h;
            h = (_Float16)x0.x; ah[0] = h; al[0] = (_Float16)(x0.x - (float)h);
            h = (_Float16)x0.y; ah[1] = h; al[1] = (_Float16)(x0.y - (float)h);
            h = (_Float16)x0.z; ah[2] = h; al[2] = (_Float16)(x0.z - (float)h);
            h = (_Float16)x0.w; ah[3] = h; al[3] = (_Float16)(x0.w - (float)h);
            h = (_Float16)x1.x; ah[4] = h; al[4] = (_Float16)(x1.x - (float)h);
            h = (_Float16)x1.y; ah[5] = h; al[5] = (_Float16)(x1.y - (float)h);
            h = (_Float16)x1.z; ah[6] = h; al[6] = (_Float16)(x1.z - (float)h);
            h = (_Float16)x1.w; ah[7] = h; al[7] = (_Float16)(x1.w - (float)h);
        }
        const int chb = ks * 4 + lg;
#pragma unroll
        for (int ct = 0; ct < 8; ++ct) {
            const int n = ct * 16 + l15;
            const int off = n * C + ((chb ^ l15) << 3);
            half8 bh = *(const half8*)&WtH[off];
            half8 bl = *(const half8*)&WtL[off];
            acc[ct] = __builtin_amdgcn_mfma_f32_16x16x32_f16(ah, bh, acc[ct], 0, 0, 0);
            acc[ct] = __builtin_amdgcn_mfma_f32_16x16x32_f16(al, bh, acc[ct], 0, 0, 0);
            acc[ct] = __builtin_amdgcn_mfma_f32_16x16x32_f16(ah, bl, acc[ct], 0, 0, 0);
        }
    }

    // C layout: col = lane&15, row = (lane>>4)*4 + reg
    const int rowC = blockIdx.x * 64 + wv * 16 + lg * 4;
#pragma unroll
    for (int r = 0; r < 4; ++r) {
        int row = rowC + r;
        if (row >= M) continue;
        float s = dinv[row];
#pragma unroll
        for (int ct = 0; ct < 8; ++ct) {
            Hs16[(size_t)row * C + ct * 16 + l15] = (_Float16)(acc[ct][r] * s);
        }
    }
}

// ---------------------------------------------------------------------------
// fused aggregation: Out[i] = relu(dinv[i]*(Hs[i] + sum_{j in N(i)} Hs[j]) + b)
// 32 lanes per node; all terms gathered as fp16 (8 B/lane), fp32 accumulate.
__global__ __launch_bounds__(256) void k_aggf(const _Float16* __restrict__ Hs16,
                                              const int* __restrict__ rowptr,
                                              const unsigned short* __restrict__ col,
                                              const float* __restrict__ dinv,
                                              const float* __restrict__ b,
                                              float* __restrict__ Out, int N) {
    const int node = blockIdx.x * 8 + (threadIdx.x >> 5);
    const int lane = threadIdx.x & 31;
    if (node >= N) return;
    const uint2* __restrict__ H16 = (const uint2*)Hs16;  // row stride 32 uint2

    uint2 qs = H16[(size_t)node * 32 + lane];  // self (Hs already row-scaled)
    float2 sa = __half22float2(*(__half2*)&qs.x);
    float2 sb = __half22float2(*(__half2*)&qs.y);
    float4 acc = make_float4(sa.x, sa.y, sb.x, sb.y);

    const int e0 = rowptr[node], e1 = rowptr[node + 1];
    int j = e0;
    for (; j + 4 <= e1; j += 4) {
        int n0 = col[j + 0], n1 = col[j + 1], n2 = col[j + 2], n3 = col[j + 3];
        uint2 q0 = H16[(size_t)n0 * 32 + lane];
        uint2 q1 = H16[(size_t)n1 * 32 + lane];
        uint2 q2 = H16[(size_t)n2 * 32 + lane];
        uint2 q3 = H16[(size_t)n3 * 32 + lane];
        float2 a0 = __half22float2(*(__half2*)&q0.x), b0 = __half22float2(*(__half2*)&q0.y);
        float2 a1 = __half22float2(*(__half2*)&q1.x), b1_ = __half22float2(*(__half2*)&q1.y);
        float2 a2 = __half22float2(*(__half2*)&q2.x), b2_ = __half22float2(*(__half2*)&q2.y);
        float2 a3 = __half22float2(*(__half2*)&q3.x), b3_ = __half22float2(*(__half2*)&q3.y);
        acc.x += (a0.x + a1.x) + (a2.x + a3.x);
        acc.y += (a0.y + a1.y) + (a2.y + a3.y);
        acc.z += (b0.x + b1_.x) + (b2_.x + b3_.x);
        acc.w += (b0.y + b1_.y) + (b2_.y + b3_.y);
    }
    for (; j < e1; ++j) {
        int n = col[j];
        uint2 q = H16[(size_t)n * 32 + lane];
        float2 a = __half22float2(*(__half2*)&q.x);
        float2 c = __half22float2(*(__half2*)&q.y);
        acc.x += a.x; acc.y += a.y; acc.z += c.x; acc.w += c.y;
    }
    const float s = dinv[node];
    const float4 bb = *(const float4*)(b + lane * 4);
    float4 o;
    o.x = s * acc.x + bb.x; o.y = s * acc.y + bb.y;
    o.z = s * acc.z + bb.z; o.w = s * acc.w + bb.w;
    o.x = o.x > 0.f ? o.x : 0.f;
    o.y = o.y > 0.f ? o.y : 0.f;
    o.z = o.z > 0.f ? o.z : 0.f;
    o.w = o.w > 0.f ? o.w : 0.f;
    ((float4*)Out)[(size_t)node * 32 + lane] = o;
}

// ---------------------------------------------------------------------------
// classifier: out[i, j] = H[i,:] . Wl[:, j] + bl[j]   (j < 10), float4 h reads
__global__ __launch_bounds__(256) void k_final(const float* __restrict__ H,
                                               const float* __restrict__ Wl,
                                               const float* __restrict__ bl,
                                               float* __restrict__ out, int M) {
    __shared__ float wl[C * 10];
    __shared__ float bls[16];
    for (int i = threadIdx.x; i < C * 10; i += 256) wl[i] = Wl[i];
    if (threadIdx.x < 10) bls[threadIdx.x] = bl[threadIdx.x];
    __syncthreads();

    long long g = (long long)blockIdx.x * 256 + threadIdx.x;
    int i = (int)(g >> 4);
    int j = (int)(g & 15);
    if (i >= M || j >= 10) return;
    const float4* h4 = (const float4*)(H + (size_t)i * C);
    float acc = bls[j];
#pragma unroll 8
    for (int c4 = 0; c4 < 32; ++c4) {
        float4 hv = h4[c4];
        int cb = c4 * 4;
        acc += hv.x * wl[(cb + 0) * 10 + j] + hv.y * wl[(cb + 1) * 10 + j] +
               hv.z * wl[(cb + 2) * 10 + j] + hv.w * wl[(cb + 3) * 10 + j];
    }
    out[(size_t)i * 10 + j] = acc;
}

// ---------------------------------------------------------------------------
extern "C" void kernel_launch(void* const* d_in, const int* in_sizes, int n_in,
                              void* d_out, int out_size, void* d_ws, size_t ws_size,
                              hipStream_t stream) {
    const float* x  = (const float*)d_in[0];
    const int*   ei = (const int*)d_in[1];
    const float* W1 = (const float*)d_in[2];
    const float* b1 = (const float*)d_in[3];
    const float* W2 = (const float*)d_in[4];
    const float* b2 = (const float*)d_in[5];
    const float* Wl = (const float*)d_in[6];
    const float* bl = (const float*)d_in[7];
    float* out = (float*)d_out;

    const int N = in_sizes[0] / C;   // 50000
    const int E = in_sizes[1] / 2;   // 800000
    const int* src = ei;
    const int* dst = ei + E;

    char* p = (char*)d_ws;
    _Float16* bufHs16 = (_Float16*)p;  p += (size_t)N * C * 2;
    float*    bufT    = (float*)p;     p += (size_t)N * C * 4;
    int*      cnt     = (int*)p;       p += (size_t)N * 4;
    int*      rowptr  = (int*)p;       p += (size_t)(N + 1) * 4;
    float*    dinv    = (float*)p;     p += (size_t)N * 4;
    int*      partials= (int*)p;       p += 1024;
    unsigned short* rank   = (unsigned short*)p;  p += (size_t)E * 2;
    unsigned short* colidx = (unsigned short*)p;

    const int gridN   = (N + 255) / 256;       // 196
    const int gridE   = (E + 255) / 256;       // 3125
    const int gridGemm = (N + 63) / 64;        // 782
    const int gridAgg = (N + 7) / 8;           // 6250
    const int gridFin = (int)(((long long)N * 16 + 255) / 256);

    // CSR build (once; shared by both layers)
    k_zero<<<gridN, 256, 0, stream>>>(cnt, N);
    k_histr<<<gridE, 256, 0, stream>>>(dst, cnt, rank, E);
    k_scan1<<<gridN, 256, 0, stream>>>(cnt, partials, N);
    k_scan2<<<1, 256, 0, stream>>>(partials, gridN);
    k_scan3<<<gridN, 256, 0, stream>>>(cnt, partials, rowptr, dinv, N, E);
    k_fill2<<<gridE, 256, 0, stream>>>(src, dst, rank, rowptr, colidx, E);

    // layer 1
    k_gemm_mfma<<<gridGemm, 256, 0, stream>>>(x, W1, dinv, bufHs16, N);
    k_aggf<<<gridAgg, 256, 0, stream>>>(bufHs16, rowptr, colidx, dinv, b1, bufT, N);

    // layer 2
    k_gemm_mfma<<<gridGemm, 256, 0, stream>>>(bufT, W2, dinv, bufHs16, N);
    k_aggf<<<gridAgg, 256, 0, stream>>>(bufHs16, rowptr, colidx, dinv, b2, bufT, N);

    // classifier
    k_final<<<gridFin, 256, 0, stream>>>(bufT, Wl, bl, out, N);
}